// Round 12
// baseline (589.772 us; speedup 1.0000x reference)
//
#include <hip/hip_runtime.h>
#include <hip/hip_fp16.h>
#include <math.h>

#define BSH    9          // bucket = 512 nodes
#define BNODES 512
#define NBMAX  128
#define CAP2   24576      // per-bucket stage capacity
#define ECHUNK 6144       // edges per k_bin block

typedef short bf16x8 __attribute__((ext_vector_type(8)));
typedef float f32x4 __attribute__((ext_vector_type(4)));

__device__ __forceinline__ unsigned f2b(float f) {   // float -> bf16 bits, RTN-even
    union { float f; unsigned u; } x; x.f = f;
    return (x.u + 0x7fffu + ((x.u >> 16) & 1u)) >> 16;
}

// ---------------- zero ----------------

__global__ __launch_bounds__(256) void k_zero(int* __restrict__ p, int n) {
    int i = blockIdx.x * 256 + threadIdx.x;
    if (i < n) p[i] = 0;
}

// ---------------- casts ----------------

__global__ __launch_bounds__(256) void k_castx(const float4* __restrict__ x, uint4* __restrict__ xb, int n8) {
    int i = blockIdx.x * 256 + threadIdx.x;
    if (i >= n8) return;
    float4 f0 = x[2 * i], f1 = x[2 * i + 1];
    uint4 o;
    o.x = f2b(f0.x) | (f2b(f0.y) << 16);
    o.y = f2b(f0.z) | (f2b(f0.w) << 16);
    o.z = f2b(f1.x) | (f2b(f1.y) << 16);
    o.w = f2b(f1.z) | (f2b(f1.w) << 16);
    xb[i] = o;
}

// fused: w1t[n*256+k]=bf16(W1[k*256+n]); w2t[n*256+k]=bf16(W2[k*48+n])
__global__ __launch_bounds__(256) void k_castw(const float* __restrict__ W1, const float* __restrict__ W2,
                                               unsigned short* __restrict__ w1t, unsigned short* __restrict__ w2t) {
    int i = blockIdx.x * 256 + threadIdx.x;
    if (i < 65536) {
        int n = i >> 8, k = i & 255;
        w1t[i] = (unsigned short)f2b(W1[k * 256 + n]);
    } else if (i < 65536 + 12288) {
        int j = i - 65536;
        int n = j >> 8, k = j & 255;
        w2t[j] = (unsigned short)f2b(W2[k * 48 + n]);
    }
}

// ---------------- pass 1: block-local binning by dst>>9 ----------------

__global__ __launch_bounds__(256) void k_bin(const int* __restrict__ src, const int* __restrict__ dst,
                                             int* __restrict__ bktcnt, unsigned* __restrict__ stage,
                                             int E, int NB) {
    __shared__ unsigned ecache[ECHUNK];
    __shared__ int lcnt[NBMAX], lbase[NBMAX], lcur[NBMAX];
    const int t = threadIdx.x;
    for (int i = t; i < NBMAX; i += 256) { lcnt[i] = 0; lcur[i] = 0; }
    const int e0 = blockIdx.x * ECHUNK;
    const int m = min(ECHUNK, E - e0);
    __syncthreads();
    for (int i = t; i < m; i += 256) {
        int s = src[e0 + i], d = dst[e0 + i];
        ecache[i] = ((unsigned)d << 16) | (unsigned)s;
        atomicAdd(&lcnt[d >> BSH], 1);
    }
    __syncthreads();
    if (t < NB) lbase[t] = lcnt[t] ? atomicAdd(&bktcnt[t], lcnt[t]) : 0;
    __syncthreads();
    for (int i = t; i < m; i += 256) {
        unsigned p = ecache[i];
        int b = (int)(p >> (16 + BSH));
        int pos = lbase[b] + atomicAdd(&lcur[b], 1);
        if (pos < CAP2) stage[(size_t)b * CAP2 + pos] = p;
    }
}

// ---------------- pass 2a: degrees per bucket + fused dinv/dinv2/sdeg ----------------

__global__ __launch_bounds__(512) void k_cnt(const unsigned* __restrict__ stage,
                                             const int* __restrict__ bktcnt,
                                             int* __restrict__ cnt,
                                             float* __restrict__ dinv, float* __restrict__ dinv2,
                                             float* __restrict__ sdeg, int N) {
    __shared__ int dcnt[BNODES];
    const int b = blockIdx.x, t = threadIdx.x;
    dcnt[t] = 0;
    __syncthreads();
    const int m = min(bktcnt[b], CAP2);
    const unsigned* st = stage + (size_t)b * CAP2;
    for (int i = t; i < m; i += 512)
        atomicAdd(&dcnt[(st[i] >> 16) & (BNODES - 1)], 1);
    __syncthreads();
    int node = b * BNODES + t;
    if (node <= N) {                       // include sentinel N (deg 0 -> row stays zero)
        int c = dcnt[t];
        cnt[node] = c;
        float d = (float)c + 1.0f;
        float r = rsqrtf(d);
        dinv[node] = r;
        dinv2[node] = r * r;
        sdeg[node] = d * r;
    }
}

// ---------------- scan over 32-padded row capacities ----------------

__global__ __launch_bounds__(256) void k_scan1(const int* __restrict__ cnt, int* __restrict__ rowptr,
                                               int* __restrict__ blk, int NT) {
    __shared__ int s[256];
    int t = threadIdx.x, i = blockIdx.x * 256 + t;
    int v = (i < NT) ? ((cnt[i] + 31) & ~31) : 0;   // pad rows to multiple of 32
    s[t] = v; __syncthreads();
#pragma unroll
    for (int off = 1; off < 256; off <<= 1) {
        int x = (t >= off) ? s[t - off] : 0; __syncthreads();
        s[t] += x; __syncthreads();
    }
    if (i < NT) rowptr[i] = s[t] - v;
    if (t == 255) blk[blockIdx.x] = s[255];
}

__global__ __launch_bounds__(256) void k_scan2(int* __restrict__ blk, int nb) {
    __shared__ int s[256];
    int t = threadIdx.x;
    int v = (t < nb) ? blk[t] : 0;
    s[t] = v; __syncthreads();
#pragma unroll
    for (int off = 1; off < 256; off <<= 1) {
        int x = (t >= off) ? s[t - off] : 0; __syncthreads();
        s[t] += x; __syncthreads();
    }
    if (t < nb) blk[t] = s[t] - v;
}

__global__ __launch_bounds__(256) void k_scan3(int* __restrict__ rowptr, const int* __restrict__ blk, int NT) {
    int i = blockIdx.x * 256 + threadIdx.x;
    if (i < NT) rowptr[i] += blk[blockIdx.x];
}

// ---------------- pass 2b: place into CSR (ushort) + pad ----------------

__global__ __launch_bounds__(512) void k_place(const unsigned* __restrict__ stage,
                                               const int* __restrict__ bktcnt,
                                               const int* __restrict__ rowptr,
                                               unsigned short* __restrict__ csr, int N) {
    __shared__ int lcur[BNODES];
    const int b = blockIdx.x, t = threadIdx.x;
    const int node = b * BNODES + t;
    lcur[t] = (node < N) ? rowptr[node] : 0;
    __syncthreads();
    const int m = min(bktcnt[b], CAP2);
    const unsigned* st = stage + (size_t)b * CAP2;
    for (int i = t; i < m; i += 512) {
        unsigned p = st[i];
        int dl = (int)((p >> 16) & (BNODES - 1));
        int pos = atomicAdd(&lcur[dl], 1);
        csr[pos] = (unsigned short)(p & 0xffffu);
    }
    __syncthreads();
    if (node < N) {
        int e1 = rowptr[node + 1];
        for (int i = lcur[t]; i < e1; ++i) csr[i] = (unsigned short)N;
    }
}

// ---------------- MFMA GEMM1: h1b = bf16(relu(xb @ W1 + b1)) ----------------
// 128x128 tile, BK=32; LDS-coalesced epilogue (full 128B/thread stores -> no partial-sector writeback).

__global__ __launch_bounds__(256) void k_mgemm1(const unsigned short* __restrict__ xb,
                                                const unsigned short* __restrict__ w1t,
                                                const float* __restrict__ bias,
                                                unsigned short* __restrict__ h1b, int M) {
    __shared__ unsigned short sbuf[128 * 136];   // K-loop: As=first 5120, Bs=next 5120; epilogue: 128x136 tile
    unsigned short* As = sbuf;
    unsigned short* Bs = sbuf + 128 * 40;
    const int t = threadIdx.x;
    const int bm = blockIdx.x * 128;
    const int bn = blockIdx.y * 128;
    const int w = t >> 6, lane = t & 63;
    const int q = lane >> 4, l16 = lane & 15;

    f32x4 acc[2][8] = {};
    const int ar0 = t >> 2;
    const int kc  = t & 3;
    const int swz_st = ((kc ^ (ar0 & 3)) * 8);
    int gr0 = bm + ar0;       if (gr0 >= M) gr0 = M - 1;
    int gr1 = bm + ar0 + 64;  if (gr1 >= M) gr1 = M - 1;
    const int swz_rd = (q ^ (l16 & 3)) * 8;

    for (int k0 = 0; k0 < 256; k0 += 32) {
        uint4 a0 = *(const uint4*)&xb[(size_t)gr0 * 256 + k0 + kc * 8];
        uint4 a1 = *(const uint4*)&xb[(size_t)gr1 * 256 + k0 + kc * 8];
        uint4 b0 = *(const uint4*)&w1t[(size_t)(bn + ar0) * 256 + k0 + kc * 8];
        uint4 b1 = *(const uint4*)&w1t[(size_t)(bn + ar0 + 64) * 256 + k0 + kc * 8];
        __syncthreads();
        *(uint4*)&As[ar0 * 40 + swz_st] = a0;
        *(uint4*)&As[(ar0 + 64) * 40 + swz_st] = a1;
        *(uint4*)&Bs[ar0 * 40 + swz_st] = b0;
        *(uint4*)&Bs[(ar0 + 64) * 40 + swz_st] = b1;
        __syncthreads();
        bf16x8 af0 = *(bf16x8*)&As[(w * 32 + l16) * 40 + swz_rd];
        bf16x8 af1 = *(bf16x8*)&As[(w * 32 + 16 + l16) * 40 + swz_rd];
#pragma unroll
        for (int j = 0; j < 8; ++j) {
            bf16x8 bf = *(bf16x8*)&Bs[(j * 16 + l16) * 40 + swz_rd];
            acc[0][j] = __builtin_amdgcn_mfma_f32_16x16x32_bf16(af0, bf, acc[0][j], 0, 0, 0);
            acc[1][j] = __builtin_amdgcn_mfma_f32_16x16x32_bf16(af1, bf, acc[1][j], 0, 0, 0);
        }
    }
    // epilogue: fragments -> LDS tile -> coalesced 128B/thread stores
    __syncthreads();
#pragma unroll
    for (int j = 0; j < 8; ++j) {
        int col = j * 16 + l16;
        float bb = bias[bn + col];
#pragma unroll
        for (int i = 0; i < 2; ++i) {
#pragma unroll
            for (int r = 0; r < 4; ++r) {
                float v = fmaxf(acc[i][j][r] + bb, 0.f);
                sbuf[(w * 32 + i * 16 + q * 4 + r) * 136 + col] = (unsigned short)f2b(v);
            }
        }
    }
    __syncthreads();
    const int row = t >> 1;
    const int ch = (t & 1) * 64;
    if (bm + row < M) {
#pragma unroll
        for (int i = 0; i < 8; ++i) {
            uint4 v = *(uint4*)&sbuf[row * 136 + ch + i * 8];
            *(uint4*)&h1b[(size_t)(bm + row) * 256 + bn + ch + i * 8] = v;
        }
    }
}

// ---------------- MFMA GEMM2: u0 = fp16(dinv .* (h1b @ W2 + b2)) ----------------

__global__ __launch_bounds__(256) void k_mgemm2(const unsigned short* __restrict__ h1b,
                                                const unsigned short* __restrict__ w2t,
                                                const float* __restrict__ bias,
                                                const float* __restrict__ dinv,
                                                __half* __restrict__ u0, int M) {
    __shared__ unsigned short As[128 * 40];
    __shared__ unsigned short Bs[48 * 40];
    const int t = threadIdx.x;
    const int bm = blockIdx.x * 128;
    const int w = t >> 6, lane = t & 63;
    const int q = lane >> 4, l16 = lane & 15;

    f32x4 acc[2][3] = {};
    const int ar0 = t >> 2;
    const int kc  = t & 3;
    const int swz_st = ((kc ^ (ar0 & 3)) * 8);
    int gr0 = bm + ar0;      if (gr0 >= M) gr0 = M - 1;
    int gr1 = bm + ar0 + 64; if (gr1 >= M) gr1 = M - 1;
    const int swz_rd = (q ^ (l16 & 3)) * 8;

    for (int k0 = 0; k0 < 256; k0 += 32) {
        uint4 a0 = *(const uint4*)&h1b[(size_t)gr0 * 256 + k0 + kc * 8];
        uint4 a1 = *(const uint4*)&h1b[(size_t)gr1 * 256 + k0 + kc * 8];
        uint4 bv;
        if (t < 192) bv = *(const uint4*)&w2t[(size_t)ar0 * 256 + k0 + kc * 8];
        __syncthreads();
        *(uint4*)&As[ar0 * 40 + swz_st] = a0;
        *(uint4*)&As[(ar0 + 64) * 40 + swz_st] = a1;
        if (t < 192) *(uint4*)&Bs[ar0 * 40 + swz_st] = bv;
        __syncthreads();
        bf16x8 af0 = *(bf16x8*)&As[(w * 32 + l16) * 40 + swz_rd];
        bf16x8 af1 = *(bf16x8*)&As[(w * 32 + 16 + l16) * 40 + swz_rd];
#pragma unroll
        for (int j = 0; j < 3; ++j) {
            bf16x8 bf = *(bf16x8*)&Bs[(j * 16 + l16) * 40 + swz_rd];
            acc[0][j] = __builtin_amdgcn_mfma_f32_16x16x32_bf16(af0, bf, acc[0][j], 0, 0, 0);
            acc[1][j] = __builtin_amdgcn_mfma_f32_16x16x32_bf16(af1, bf, acc[1][j], 0, 0, 0);
        }
    }
#pragma unroll
    for (int j = 0; j < 3; ++j) {
        int col = j * 16 + l16;
        float bb = bias[col];
#pragma unroll
        for (int i = 0; i < 2; ++i) {
#pragma unroll
            for (int r = 0; r < 4; ++r) {
                int row = bm + w * 32 + i * 16 + q * 4 + r;
                if (row < M) {
                    float v = (acc[i][j][r] + bb) * dinv[row];
                    u0[(size_t)row * 48 + col] = __float2half(v);
                }
            }
        }
    }
}

// ---------------- vector-gather hop: 2 nodes per wave, 8 gathers in flight ----------------
// lane = cc*8 + j (cc=colchunk 0..5 + 2 dup, j=edge 0..7); per node 4 independent uint4 gathers.

__global__ __launch_bounds__(256) void k_hop(const __half* __restrict__ u, __half* __restrict__ unxt,
                                             const int* __restrict__ rowptr,
                                             const unsigned short* __restrict__ csr,
                                             const float* __restrict__ dinv2, int NT) {
    const int w = threadIdx.x >> 6;
    const int n0 = blockIdx.x * 8 + w;
    if (n0 >= NT) return;
    const int n1 = n0 + 4;
    const bool has1 = (n1 < NT);
    const int lane = threadIdx.x & 63;
    const int j = lane & 7;
    const int cc = lane >> 3;
    const bool act = cc < 6;
    const int ccs = act ? cc : 0;

    int e0a = rowptr[n0], e1a = rowptr[n0 + 1];
    int e0b = 0, e1b = 0;
    if (has1) { e0b = rowptr[n1]; e1b = rowptr[n1 + 1]; }
    const int la = e1a - e0a, lb = e1b - e0b;
    const int lmax = la > lb ? la : lb;

    float acca[8] = {0.f, 0.f, 0.f, 0.f, 0.f, 0.f, 0.f, 0.f};
    float accb[8] = {0.f, 0.f, 0.f, 0.f, 0.f, 0.f, 0.f, 0.f};

    for (int off = 0; off < lmax; off += 32) {
        const bool da = off < la, db = off < lb;
        union UU { uint4 u4; __half2 h2[4]; } g0, g1, g2, g3, h0, h1, h2x, h3;
        if (da) {
            int e = e0a + off;
            int s0 = (int)csr[e + j];
            int s1 = (int)csr[e + 8 + j];
            int s2 = (int)csr[e + 16 + j];
            int s3 = (int)csr[e + 24 + j];
            g0.u4 = *(const uint4*)(u + (size_t)s0 * 48 + ccs * 8);
            g1.u4 = *(const uint4*)(u + (size_t)s1 * 48 + ccs * 8);
            g2.u4 = *(const uint4*)(u + (size_t)s2 * 48 + ccs * 8);
            g3.u4 = *(const uint4*)(u + (size_t)s3 * 48 + ccs * 8);
        }
        if (db) {
            int e = e0b + off;
            int s0 = (int)csr[e + j];
            int s1 = (int)csr[e + 8 + j];
            int s2 = (int)csr[e + 16 + j];
            int s3 = (int)csr[e + 24 + j];
            h0.u4 = *(const uint4*)(u + (size_t)s0 * 48 + ccs * 8);
            h1.u4 = *(const uint4*)(u + (size_t)s1 * 48 + ccs * 8);
            h2x.u4 = *(const uint4*)(u + (size_t)s2 * 48 + ccs * 8);
            h3.u4 = *(const uint4*)(u + (size_t)s3 * 48 + ccs * 8);
        }
        if (da) {
#pragma unroll
            for (int i = 0; i < 4; ++i) {
                float2 fa = __half22float2(g0.h2[i]);
                float2 fb = __half22float2(g1.h2[i]);
                float2 fc = __half22float2(g2.h2[i]);
                float2 fd = __half22float2(g3.h2[i]);
                acca[2 * i]     += (fa.x + fb.x) + (fc.x + fd.x);
                acca[2 * i + 1] += (fa.y + fb.y) + (fc.y + fd.y);
            }
        }
        if (db) {
#pragma unroll
            for (int i = 0; i < 4; ++i) {
                float2 fa = __half22float2(h0.h2[i]);
                float2 fb = __half22float2(h1.h2[i]);
                float2 fc = __half22float2(h2x.h2[i]);
                float2 fd = __half22float2(h3.h2[i]);
                accb[2 * i]     += (fa.x + fb.x) + (fc.x + fd.x);
                accb[2 * i + 1] += (fa.y + fb.y) + (fc.y + fd.y);
            }
        }
    }
#pragma unroll
    for (int off = 1; off < 8; off <<= 1) {
#pragma unroll
        for (int i = 0; i < 8; ++i) {
            acca[i] += __shfl_xor(acca[i], off);
            accb[i] += __shfl_xor(accb[i], off);
        }
    }
    if (act && j == 0) {
        union UU { uint4 u4; __half2 h2[4]; } sv, ov;
        sv.u4 = *(const uint4*)(u + (size_t)n0 * 48 + cc * 8);    // self-loop term
        float w2 = dinv2[n0];
#pragma unroll
        for (int i = 0; i < 4; ++i) {
            float2 sf = __half22float2(sv.h2[i]);
            float2 r;
            r.x = (acca[2 * i]     + sf.x) * w2;
            r.y = (acca[2 * i + 1] + sf.y) * w2;
            ov.h2[i] = __float22half2_rn(r);
        }
        *(uint4*)(unxt + (size_t)n0 * 48 + cc * 8) = ov.u4;
        if (has1) {
            sv.u4 = *(const uint4*)(u + (size_t)n1 * 48 + cc * 8);
            w2 = dinv2[n1];
#pragma unroll
            for (int i = 0; i < 4; ++i) {
                float2 sf = __half22float2(sv.h2[i]);
                float2 r;
                r.x = (accb[2 * i]     + sf.x) * w2;
                r.y = (accb[2 * i + 1] + sf.y) * w2;
                ov.h2[i] = __float22half2_rn(r);
            }
            *(uint4*)(unxt + (size_t)n1 * 48 + cc * 8) = ov.u4;
        }
    }
}

// ---------------- final: out = log_softmax(sdeg * sum_k temp[k]*u_k) ----------------

__global__ __launch_bounds__(256) void k_final(const __half* __restrict__ u0, const __half* __restrict__ u1,
                                               size_t S, const float* __restrict__ sdeg,
                                               const float* __restrict__ temp,
                                               float* __restrict__ out, int N) {
    int w = (blockIdx.x * 256 + threadIdx.x) >> 6;
    int lane = threadIdx.x & 63;
    if (w >= N) return;
    size_t base = (size_t)w * 48 + lane;
    float val = 0.f, m = -INFINITY;
    if (lane < 48) {
        float acc = temp[0] * __half2float(u0[base]);
        const __half* uk = u1;
#pragma unroll
        for (int k = 1; k <= 10; ++k) {
            acc += temp[k] * __half2float(uk[base]);
            uk += S;
        }
        val = acc * sdeg[w];
        m = val;
    }
#pragma unroll
    for (int off = 32; off; off >>= 1) m = fmaxf(m, __shfl_xor(m, off));
    float ex = (lane < 48) ? __expf(val - m) : 0.f;
    float s = ex;
#pragma unroll
    for (int off = 32; off; off >>= 1) s += __shfl_xor(s, off);
    if (lane < 48) out[(size_t)w * 48 + lane] = val - m - __logf(s);
}

// ---------------- launch ----------------

extern "C" void kernel_launch(void* const* d_in, const int* in_sizes, int n_in,
                              void* d_out, int out_size, void* d_ws, size_t ws_size,
                              hipStream_t stream) {
    const float* x    = (const float*)d_in[0];
    const int*   ei   = (const int*)d_in[1];
    const float* W1   = (const float*)d_in[2];
    const float* b1   = (const float*)d_in[3];
    const float* W2   = (const float*)d_in[4];
    const float* b2   = (const float*)d_in[5];
    const float* temp = (const float*)d_in[6];
    float* out = (float*)d_out;

    const int N = in_sizes[0] / 256;
    const int E = in_sizes[1] / 2;
    const int* src = ei;
    const int* dst = ei + E;

    const int NT  = N + 1;                  // + sentinel node (u rows kept zero)
    const int NT2 = N + 2;
    const int NB  = (NT + BNODES - 1) >> BSH;

    // workspace layout
    char* w8 = (char*)d_ws;
    size_t NP = (size_t)((NT2 + 63) & ~63);
    int*   cnt     = (int*)w8;                          // NP (+128 bktcnt)
    int*   bktcnt  = cnt + NP;                          // 128
    int*   rowptr  = bktcnt + 128;                      // NP
    int*   blk     = rowptr + NP;                       // 256
    float* dinv    = (float*)(blk + 256);               // NP
    float* dinv2   = dinv + NP;                         // NP
    float* sdeg    = dinv2 + NP;                        // NP
    unsigned short* csr = (unsigned short*)(sdeg + NP); // E + 32*NT shorts
    size_t csr_i   = (((size_t)E + 32 * NT) / 2 + 32 + 63) & ~(size_t)63;  // ints
    unsigned short* w1t = (unsigned short*)((int*)(sdeg + NP) + csr_i);    // 65536 shorts
    unsigned short* w2t = w1t + 65536;                  // 12288 shorts (+pad)
    unsigned short* xb  = w2t + 12288 + 64;             // N*256 shorts (25.6MB)
    size_t S       = ((size_t)NT * 48 + 127) & ~(size_t)127;  // u-slab stride (halves)
    __half* u0     = (__half*)(xb + (size_t)N * 256);   // S halves
    unsigned short* h1b = (unsigned short*)(u0 + S);    // N*256 shorts (gemm1 out)
    unsigned* stage = (unsigned*)h1b;                   // NB*CAP2 uints ⊂ h1b (dead pre-gemm)
    __half* u1     = (__half*)(h1b + (size_t)N * 256);  // u1..u10 = 10*S halves

    const int nbS = (NT2 + 255) / 256;

    // CSR build
    k_zero  <<<(int)((NP + 128 + 255) / 256), 256, 0, stream>>>(cnt, (int)(NP + 128));
    k_bin   <<<(E + ECHUNK - 1) / ECHUNK, 256, 0, stream>>>(src, dst, bktcnt, stage, E, NB);
    k_cnt   <<<NB, 512, 0, stream>>>(stage, bktcnt, cnt, dinv, dinv2, sdeg, N);
    k_scan1 <<<nbS, 256, 0, stream>>>(cnt, rowptr, blk, NT2);
    k_scan2 <<<1, 256, 0, stream>>>(blk, nbS);
    k_scan3 <<<nbS, 256, 0, stream>>>(rowptr, blk, NT2);
    k_place <<<NB, 512, 0, stream>>>(stage, bktcnt, rowptr, csr, N);

    // casts
    k_castx <<<(N * 256 / 8 + 255) / 256, 256, 0, stream>>>((const float4*)x, (uint4*)xb, N * 256 / 8);
    k_castw <<<(65536 + 12288 + 255) / 256, 256, 0, stream>>>(W1, W2, w1t, w2t);

    // MLP head on MFMA
    dim3 g1((N + 127) / 128, 2);
    k_mgemm1<<<g1, 256, 0, stream>>>(xb, w1t, b1, h1b, N);
    k_mgemm2<<<(N + 127) / 128, 256, 0, stream>>>(h1b, w2t, b2, dinv, u0, N);
    k_zero  <<<1, 64, 0, stream>>>((int*)(u0 + (size_t)N * 48), 24);   // sentinel u0 row

    // K-hop propagation: 2 nodes/wave, 8 gathers in flight
    const int hopBlocks = (NT + 7) / 8;
    for (int k = 0; k < 10; ++k) {
        const __half* cur = (k == 0) ? u0 : (u1 + (size_t)(k - 1) * S);
        __half* nxt = u1 + (size_t)k * S;
        k_hop<<<hopBlocks, 256, 0, stream>>>(cur, nxt, rowptr, csr, dinv2, NT);
    }

    k_final<<<(N + 3) / 4, 256, 0, stream>>>(u0, u1, S, sdeg, temp, out, N);
}

// Round 13
// 506.831 us; speedup vs baseline: 1.1636x; 1.1636x over previous
//
#include <hip/hip_runtime.h>
#include <hip/hip_fp16.h>
#include <math.h>

#define BSH    9          // bucket = 512 nodes
#define BNODES 512
#define NBMAX  128
#define CAP2   24576      // per-bucket stage capacity
#define ECHUNK 6144       // edges per k_bin block

typedef short bf16x8 __attribute__((ext_vector_type(8)));
typedef float f32x4 __attribute__((ext_vector_type(4)));

__device__ __forceinline__ unsigned f2b(float f) {   // float -> bf16 bits, RTN-even
    union { float f; unsigned u; } x; x.f = f;
    return (x.u + 0x7fffu + ((x.u >> 16) & 1u)) >> 16;
}

// ---------------- zero ----------------

__global__ __launch_bounds__(256) void k_zero(int* __restrict__ p, int n) {
    int i = blockIdx.x * 256 + threadIdx.x;
    if (i < n) p[i] = 0;
}

// ---------------- casts ----------------

__global__ __launch_bounds__(256) void k_castx(const float4* __restrict__ x, uint4* __restrict__ xb, int n8) {
    int i = blockIdx.x * 256 + threadIdx.x;
    if (i >= n8) return;
    float4 f0 = x[2 * i], f1 = x[2 * i + 1];
    uint4 o;
    o.x = f2b(f0.x) | (f2b(f0.y) << 16);
    o.y = f2b(f0.z) | (f2b(f0.w) << 16);
    o.z = f2b(f1.x) | (f2b(f1.y) << 16);
    o.w = f2b(f1.z) | (f2b(f1.w) << 16);
    xb[i] = o;
}

// fused: w1t[n*256+k]=bf16(W1[k*256+n]); w2t[n*256+k]=bf16(W2[k*48+n])
__global__ __launch_bounds__(256) void k_castw(const float* __restrict__ W1, const float* __restrict__ W2,
                                               unsigned short* __restrict__ w1t, unsigned short* __restrict__ w2t) {
    int i = blockIdx.x * 256 + threadIdx.x;
    if (i < 65536) {
        int n = i >> 8, k = i & 255;
        w1t[i] = (unsigned short)f2b(W1[k * 256 + n]);
    } else if (i < 65536 + 12288) {
        int j = i - 65536;
        int n = j >> 8, k = j & 255;
        w2t[j] = (unsigned short)f2b(W2[k * 48 + n]);
    }
}

// ---------------- pass 1: block-local binning by dst>>9 ----------------

__global__ __launch_bounds__(256) void k_bin(const int* __restrict__ src, const int* __restrict__ dst,
                                             int* __restrict__ bktcnt, unsigned* __restrict__ stage,
                                             int E, int NB) {
    __shared__ unsigned ecache[ECHUNK];
    __shared__ int lcnt[NBMAX], lbase[NBMAX], lcur[NBMAX];
    const int t = threadIdx.x;
    for (int i = t; i < NBMAX; i += 256) { lcnt[i] = 0; lcur[i] = 0; }
    const int e0 = blockIdx.x * ECHUNK;
    const int m = min(ECHUNK, E - e0);
    __syncthreads();
    for (int i = t; i < m; i += 256) {
        int s = src[e0 + i], d = dst[e0 + i];
        ecache[i] = ((unsigned)d << 16) | (unsigned)s;
        atomicAdd(&lcnt[d >> BSH], 1);
    }
    __syncthreads();
    if (t < NB) lbase[t] = lcnt[t] ? atomicAdd(&bktcnt[t], lcnt[t]) : 0;
    __syncthreads();
    for (int i = t; i < m; i += 256) {
        unsigned p = ecache[i];
        int b = (int)(p >> (16 + BSH));
        int pos = lbase[b] + atomicAdd(&lcur[b], 1);
        if (pos < CAP2) stage[(size_t)b * CAP2 + pos] = p;
    }
}

// ---------------- pass 2a: degrees per bucket + fused dinv/dinv2/sdeg ----------------

__global__ __launch_bounds__(512) void k_cnt(const unsigned* __restrict__ stage,
                                             const int* __restrict__ bktcnt,
                                             int* __restrict__ cnt,
                                             float* __restrict__ dinv, float* __restrict__ dinv2,
                                             float* __restrict__ sdeg, int N) {
    __shared__ int dcnt[BNODES];
    const int b = blockIdx.x, t = threadIdx.x;
    dcnt[t] = 0;
    __syncthreads();
    const int m = min(bktcnt[b], CAP2);
    const unsigned* st = stage + (size_t)b * CAP2;
    for (int i = t; i < m; i += 512)
        atomicAdd(&dcnt[(st[i] >> 16) & (BNODES - 1)], 1);
    __syncthreads();
    int node = b * BNODES + t;
    if (node <= N) {                       // include sentinel N (deg 0 -> row stays zero)
        int c = dcnt[t];
        cnt[node] = c;
        float d = (float)c + 1.0f;
        float r = rsqrtf(d);
        dinv[node] = r;
        dinv2[node] = r * r;
        sdeg[node] = d * r;
    }
}

// ---------------- scan over 32-padded row capacities ----------------

__global__ __launch_bounds__(256) void k_scan1(const int* __restrict__ cnt, int* __restrict__ rowptr,
                                               int* __restrict__ blk, int NT) {
    __shared__ int s[256];
    int t = threadIdx.x, i = blockIdx.x * 256 + t;
    int v = (i < NT) ? ((cnt[i] + 31) & ~31) : 0;   // pad rows to multiple of 32
    s[t] = v; __syncthreads();
#pragma unroll
    for (int off = 1; off < 256; off <<= 1) {
        int x = (t >= off) ? s[t - off] : 0; __syncthreads();
        s[t] += x; __syncthreads();
    }
    if (i < NT) rowptr[i] = s[t] - v;
    if (t == 255) blk[blockIdx.x] = s[255];
}

__global__ __launch_bounds__(256) void k_scan2(int* __restrict__ blk, int nb) {
    __shared__ int s[256];
    int t = threadIdx.x;
    int v = (t < nb) ? blk[t] : 0;
    s[t] = v; __syncthreads();
#pragma unroll
    for (int off = 1; off < 256; off <<= 1) {
        int x = (t >= off) ? s[t - off] : 0; __syncthreads();
        s[t] += x; __syncthreads();
    }
    if (t < nb) blk[t] = s[t] - v;
}

__global__ __launch_bounds__(256) void k_scan3(int* __restrict__ rowptr, const int* __restrict__ blk, int NT) {
    int i = blockIdx.x * 256 + threadIdx.x;
    if (i < NT) rowptr[i] += blk[blockIdx.x];
}

// ---------------- pass 2b: place into CSR (ushort) + pad ----------------

__global__ __launch_bounds__(512) void k_place(const unsigned* __restrict__ stage,
                                               const int* __restrict__ bktcnt,
                                               const int* __restrict__ rowptr,
                                               unsigned short* __restrict__ csr, int N) {
    __shared__ int lcur[BNODES];
    const int b = blockIdx.x, t = threadIdx.x;
    const int node = b * BNODES + t;
    lcur[t] = (node < N) ? rowptr[node] : 0;
    __syncthreads();
    const int m = min(bktcnt[b], CAP2);
    const unsigned* st = stage + (size_t)b * CAP2;
    for (int i = t; i < m; i += 512) {
        unsigned p = st[i];
        int dl = (int)((p >> 16) & (BNODES - 1));
        int pos = atomicAdd(&lcur[dl], 1);
        csr[pos] = (unsigned short)(p & 0xffffu);
    }
    __syncthreads();
    if (node < N) {
        int e1 = rowptr[node + 1];
        for (int i = lcur[t]; i < e1; ++i) csr[i] = (unsigned short)N;
    }
}

// ---------------- MFMA GEMM1: h1b = bf16(relu(xb @ W1 + b1)) ----------------
// 128x128 tile, BK=32; LDS-coalesced epilogue (128B/thread stores -> no partial-sector writeback).

__global__ __launch_bounds__(256) void k_mgemm1(const unsigned short* __restrict__ xb,
                                                const unsigned short* __restrict__ w1t,
                                                const float* __restrict__ bias,
                                                unsigned short* __restrict__ h1b, int M) {
    __shared__ unsigned short sbuf[128 * 136];   // K-loop: As=first 5120, Bs=next 5120; epilogue: 128x136 tile
    unsigned short* As = sbuf;
    unsigned short* Bs = sbuf + 128 * 40;
    const int t = threadIdx.x;
    const int bm = blockIdx.x * 128;
    const int bn = blockIdx.y * 128;
    const int w = t >> 6, lane = t & 63;
    const int q = lane >> 4, l16 = lane & 15;

    f32x4 acc[2][8] = {};
    const int ar0 = t >> 2;
    const int kc  = t & 3;
    const int swz_st = ((kc ^ (ar0 & 3)) * 8);
    int gr0 = bm + ar0;       if (gr0 >= M) gr0 = M - 1;
    int gr1 = bm + ar0 + 64;  if (gr1 >= M) gr1 = M - 1;
    const int swz_rd = (q ^ (l16 & 3)) * 8;

    for (int k0 = 0; k0 < 256; k0 += 32) {
        uint4 a0 = *(const uint4*)&xb[(size_t)gr0 * 256 + k0 + kc * 8];
        uint4 a1 = *(const uint4*)&xb[(size_t)gr1 * 256 + k0 + kc * 8];
        uint4 b0 = *(const uint4*)&w1t[(size_t)(bn + ar0) * 256 + k0 + kc * 8];
        uint4 b1 = *(const uint4*)&w1t[(size_t)(bn + ar0 + 64) * 256 + k0 + kc * 8];
        __syncthreads();
        *(uint4*)&As[ar0 * 40 + swz_st] = a0;
        *(uint4*)&As[(ar0 + 64) * 40 + swz_st] = a1;
        *(uint4*)&Bs[ar0 * 40 + swz_st] = b0;
        *(uint4*)&Bs[(ar0 + 64) * 40 + swz_st] = b1;
        __syncthreads();
        bf16x8 af0 = *(bf16x8*)&As[(w * 32 + l16) * 40 + swz_rd];
        bf16x8 af1 = *(bf16x8*)&As[(w * 32 + 16 + l16) * 40 + swz_rd];
#pragma unroll
        for (int j = 0; j < 8; ++j) {
            bf16x8 bf = *(bf16x8*)&Bs[(j * 16 + l16) * 40 + swz_rd];
            acc[0][j] = __builtin_amdgcn_mfma_f32_16x16x32_bf16(af0, bf, acc[0][j], 0, 0, 0);
            acc[1][j] = __builtin_amdgcn_mfma_f32_16x16x32_bf16(af1, bf, acc[1][j], 0, 0, 0);
        }
    }
    // epilogue: fragments -> LDS tile -> coalesced 128B/thread stores
    __syncthreads();
#pragma unroll
    for (int j = 0; j < 8; ++j) {
        int col = j * 16 + l16;
        float bb = bias[bn + col];
#pragma unroll
        for (int i = 0; i < 2; ++i) {
#pragma unroll
            for (int r = 0; r < 4; ++r) {
                float v = fmaxf(acc[i][j][r] + bb, 0.f);
                sbuf[(w * 32 + i * 16 + q * 4 + r) * 136 + col] = (unsigned short)f2b(v);
            }
        }
    }
    __syncthreads();
    const int row = t >> 1;
    const int ch = (t & 1) * 64;
    if (bm + row < M) {
#pragma unroll
        for (int i = 0; i < 8; ++i) {
            uint4 v = *(uint4*)&sbuf[row * 136 + ch + i * 8];
            *(uint4*)&h1b[(size_t)(bm + row) * 256 + bn + ch + i * 8] = v;
        }
    }
}

// ---------------- MFMA GEMM2: u0 = fp16(dinv .* (h1b @ W2 + b2)) ----------------

__global__ __launch_bounds__(256) void k_mgemm2(const unsigned short* __restrict__ h1b,
                                                const unsigned short* __restrict__ w2t,
                                                const float* __restrict__ bias,
                                                const float* __restrict__ dinv,
                                                __half* __restrict__ u0, int M) {
    __shared__ unsigned short As[128 * 40];
    __shared__ unsigned short Bs[48 * 40];
    const int t = threadIdx.x;
    const int bm = blockIdx.x * 128;
    const int w = t >> 6, lane = t & 63;
    const int q = lane >> 4, l16 = lane & 15;

    f32x4 acc[2][3] = {};
    const int ar0 = t >> 2;
    const int kc  = t & 3;
    const int swz_st = ((kc ^ (ar0 & 3)) * 8);
    int gr0 = bm + ar0;      if (gr0 >= M) gr0 = M - 1;
    int gr1 = bm + ar0 + 64; if (gr1 >= M) gr1 = M - 1;
    const int swz_rd = (q ^ (l16 & 3)) * 8;

    for (int k0 = 0; k0 < 256; k0 += 32) {
        uint4 a0 = *(const uint4*)&h1b[(size_t)gr0 * 256 + k0 + kc * 8];
        uint4 a1 = *(const uint4*)&h1b[(size_t)gr1 * 256 + k0 + kc * 8];
        uint4 bv;
        if (t < 192) bv = *(const uint4*)&w2t[(size_t)ar0 * 256 + k0 + kc * 8];
        __syncthreads();
        *(uint4*)&As[ar0 * 40 + swz_st] = a0;
        *(uint4*)&As[(ar0 + 64) * 40 + swz_st] = a1;
        if (t < 192) *(uint4*)&Bs[ar0 * 40 + swz_st] = bv;
        __syncthreads();
        bf16x8 af0 = *(bf16x8*)&As[(w * 32 + l16) * 40 + swz_rd];
        bf16x8 af1 = *(bf16x8*)&As[(w * 32 + 16 + l16) * 40 + swz_rd];
#pragma unroll
        for (int j = 0; j < 3; ++j) {
            bf16x8 bf = *(bf16x8*)&Bs[(j * 16 + l16) * 40 + swz_rd];
            acc[0][j] = __builtin_amdgcn_mfma_f32_16x16x32_bf16(af0, bf, acc[0][j], 0, 0, 0);
            acc[1][j] = __builtin_amdgcn_mfma_f32_16x16x32_bf16(af1, bf, acc[1][j], 0, 0, 0);
        }
    }
#pragma unroll
    for (int j = 0; j < 3; ++j) {
        int col = j * 16 + l16;
        float bb = bias[col];
#pragma unroll
        for (int i = 0; i < 2; ++i) {
#pragma unroll
            for (int r = 0; r < 4; ++r) {
                int row = bm + w * 32 + i * 16 + q * 4 + r;
                if (row < M) {
                    float v = (acc[i][j][r] + bb) * dinv[row];
                    u0[(size_t)row * 48 + col] = __float2half(v);
                }
            }
        }
    }
}

// ---------------- vector-gather hop (round-11 proven): 1 node/wave, 32-edge unroll ----------------
// lane = cc*8 + j (cc=colchunk 0..5, j=edge 0..7); 4 independent uint4 gathers per iteration.

__global__ __launch_bounds__(256) void k_hop(const __half* __restrict__ u, __half* __restrict__ unxt,
                                             const int* __restrict__ rowptr,
                                             const unsigned short* __restrict__ csr,
                                             const float* __restrict__ dinv2, int NT) {
    int n = blockIdx.x * 4 + (threadIdx.x >> 6);
    if (n >= NT) return;
    const int lane = threadIdx.x & 63;
    const int j = lane & 7;
    const int cc = lane >> 3;
    const bool act = cc < 6;
    const int ccs = act ? cc : 0;

    float acc[8] = {0.f, 0.f, 0.f, 0.f, 0.f, 0.f, 0.f, 0.f};
    int e0 = rowptr[n], e1 = rowptr[n + 1];
    for (int e = e0; e < e1; e += 32) {
        int sa = (int)csr[e + j];
        int sb = (int)csr[e + 8 + j];
        int sc = (int)csr[e + 16 + j];
        int sd = (int)csr[e + 24 + j];
        union { uint4 u4; __half2 h2[4]; } ga, gb, gc, gd;
        ga.u4 = *(const uint4*)(u + (size_t)sa * 48 + ccs * 8);
        gb.u4 = *(const uint4*)(u + (size_t)sb * 48 + ccs * 8);
        gc.u4 = *(const uint4*)(u + (size_t)sc * 48 + ccs * 8);
        gd.u4 = *(const uint4*)(u + (size_t)sd * 48 + ccs * 8);
#pragma unroll
        for (int i = 0; i < 4; ++i) {
            float2 fa = __half22float2(ga.h2[i]);
            float2 fb = __half22float2(gb.h2[i]);
            float2 fc = __half22float2(gc.h2[i]);
            float2 fd = __half22float2(gd.h2[i]);
            acc[2 * i]     += (fa.x + fb.x) + (fc.x + fd.x);
            acc[2 * i + 1] += (fa.y + fb.y) + (fc.y + fd.y);
        }
    }
#pragma unroll
    for (int off = 1; off < 8; off <<= 1) {
#pragma unroll
        for (int i = 0; i < 8; ++i) acc[i] += __shfl_xor(acc[i], off);
    }
    if (act && j == 0) {
        union { uint4 u4; __half2 h2[4]; } sv, ov;
        sv.u4 = *(const uint4*)(u + (size_t)n * 48 + cc * 8);     // self-loop term
        float w2 = dinv2[n];
#pragma unroll
        for (int i = 0; i < 4; ++i) {
            float2 sf = __half22float2(sv.h2[i]);
            float2 r;
            r.x = (acc[2 * i]     + sf.x) * w2;
            r.y = (acc[2 * i + 1] + sf.y) * w2;
            ov.h2[i] = __float22half2_rn(r);
        }
        *(uint4*)(unxt + (size_t)n * 48 + cc * 8) = ov.u4;
    }
}

// ---------------- final: out = log_softmax(sdeg * sum_k temp[k]*u_k) ----------------

__global__ __launch_bounds__(256) void k_final(const __half* __restrict__ u0, const __half* __restrict__ u1,
                                               size_t S, const float* __restrict__ sdeg,
                                               const float* __restrict__ temp,
                                               float* __restrict__ out, int N) {
    int w = (blockIdx.x * 256 + threadIdx.x) >> 6;
    int lane = threadIdx.x & 63;
    if (w >= N) return;
    size_t base = (size_t)w * 48 + lane;
    float val = 0.f, m = -INFINITY;
    if (lane < 48) {
        float acc = temp[0] * __half2float(u0[base]);
        const __half* uk = u1;
#pragma unroll
        for (int k = 1; k <= 10; ++k) {
            acc += temp[k] * __half2float(uk[base]);
            uk += S;
        }
        val = acc * sdeg[w];
        m = val;
    }
#pragma unroll
    for (int off = 32; off; off >>= 1) m = fmaxf(m, __shfl_xor(m, off));
    float ex = (lane < 48) ? __expf(val - m) : 0.f;
    float s = ex;
#pragma unroll
    for (int off = 32; off; off >>= 1) s += __shfl_xor(s, off);
    if (lane < 48) out[(size_t)w * 48 + lane] = val - m - __logf(s);
}

// ---------------- launch ----------------

extern "C" void kernel_launch(void* const* d_in, const int* in_sizes, int n_in,
                              void* d_out, int out_size, void* d_ws, size_t ws_size,
                              hipStream_t stream) {
    const float* x    = (const float*)d_in[0];
    const int*   ei   = (const int*)d_in[1];
    const float* W1   = (const float*)d_in[2];
    const float* b1   = (const float*)d_in[3];
    const float* W2   = (const float*)d_in[4];
    const float* b2   = (const float*)d_in[5];
    const float* temp = (const float*)d_in[6];
    float* out = (float*)d_out;

    const int N = in_sizes[0] / 256;
    const int E = in_sizes[1] / 2;
    const int* src = ei;
    const int* dst = ei + E;

    const int NT  = N + 1;                  // + sentinel node (u rows kept zero)
    const int NT2 = N + 2;
    const int NB  = (NT + BNODES - 1) >> BSH;

    // workspace layout
    char* w8 = (char*)d_ws;
    size_t NP = (size_t)((NT2 + 63) & ~63);
    int*   cnt     = (int*)w8;                          // NP (+128 bktcnt)
    int*   bktcnt  = cnt + NP;                          // 128
    int*   rowptr  = bktcnt + 128;                      // NP
    int*   blk     = rowptr + NP;                       // 256
    float* dinv    = (float*)(blk + 256);               // NP
    float* dinv2   = dinv + NP;                         // NP
    float* sdeg    = dinv2 + NP;                        // NP
    unsigned short* csr = (unsigned short*)(sdeg + NP); // E + 32*NT shorts
    size_t csr_i   = (((size_t)E + 32 * NT) / 2 + 32 + 63) & ~(size_t)63;  // ints
    unsigned short* w1t = (unsigned short*)((int*)(sdeg + NP) + csr_i);    // 65536 shorts
    unsigned short* w2t = w1t + 65536;                  // 12288 shorts (+pad)
    unsigned short* xb  = w2t + 12288 + 64;             // N*256 shorts (25.6MB)
    size_t S       = ((size_t)NT * 48 + 127) & ~(size_t)127;  // u-slab stride (halves)
    __half* u0     = (__half*)(xb + (size_t)N * 256);   // S halves
    unsigned short* h1b = (unsigned short*)(u0 + S);    // N*256 shorts (gemm1 out)
    unsigned* stage = (unsigned*)h1b;                   // NB*CAP2 uints ⊂ h1b (dead pre-gemm)
    __half* u1     = (__half*)(h1b + (size_t)N * 256);  // u1..u10 = 10*S halves

    const int nbS = (NT2 + 255) / 256;

    // CSR build
    k_zero  <<<(int)((NP + 128 + 255) / 256), 256, 0, stream>>>(cnt, (int)(NP + 128));
    k_bin   <<<(E + ECHUNK - 1) / ECHUNK, 256, 0, stream>>>(src, dst, bktcnt, stage, E, NB);
    k_cnt   <<<NB, 512, 0, stream>>>(stage, bktcnt, cnt, dinv, dinv2, sdeg, N);
    k_scan1 <<<nbS, 256, 0, stream>>>(cnt, rowptr, blk, NT2);
    k_scan2 <<<1, 256, 0, stream>>>(blk, nbS);
    k_scan3 <<<nbS, 256, 0, stream>>>(rowptr, blk, NT2);
    k_place <<<NB, 512, 0, stream>>>(stage, bktcnt, rowptr, csr, N);

    // casts
    k_castx <<<(N * 256 / 8 + 255) / 256, 256, 0, stream>>>((const float4*)x, (uint4*)xb, N * 256 / 8);
    k_castw <<<(65536 + 12288 + 255) / 256, 256, 0, stream>>>(W1, W2, w1t, w2t);

    // MLP head on MFMA
    dim3 g1((N + 127) / 128, 2);
    k_mgemm1<<<g1, 256, 0, stream>>>(xb, w1t, b1, h1b, N);
    k_mgemm2<<<(N + 127) / 128, 256, 0, stream>>>(h1b, w2t, b2, dinv, u0, N);
    k_zero  <<<1, 64, 0, stream>>>((int*)(u0 + (size_t)N * 48), 24);   // sentinel u0 row

    // K-hop propagation: 1 node/wave, 32-edge unroll (proven optimum)
    const int hopBlocks = (NT + 3) / 4;
    for (int k = 0; k < 10; ++k) {
        const __half* cur = (k == 0) ? u0 : (u1 + (size_t)(k - 1) * S);
        __half* nxt = u1 + (size_t)k * S;
        k_hop<<<hopBlocks, 256, 0, stream>>>(cur, nxt, rowptr, csr, dinv2, NT);
    }

    k_final<<<(N + 3) / 4, 256, 0, stream>>>(u0, u1, S, sdeg, temp, out, N);
}